// Round 2
// baseline (216.008 us; speedup 1.0000x reference)
//
#include <hip/hip_runtime.h>

#define HH 256
#define WW 256
#define KK 81
#define PLANE (HH * WW)

// Pack [B,3,H,W] planar fp32 -> [B,H,W] float4 (c0,c1,c2,0) so each bilinear
// corner gather is a single dwordx4 covering all 3 color groups.
__global__ __launch_bounds__(256) void pack_kernel(const float* __restrict__ in,
                                                   float4* __restrict__ img) {
    int idx = blockIdx.x * 256 + threadIdx.x;   // b*PLANE + pix
    int b = idx >> 16;
    int pix = idx & 0xFFFF;
    const float* base = in + (size_t)b * 3 * PLANE + pix;
    img[idx] = make_float4(base[0], base[PLANE], base[2 * PLANE], 0.f);
}

// One block = 64-pixel strip. 4 waves split the 81 taps (21/20/20/20) and
// LDS-reduce, giving 8192 waves total (32/CU) for latency hiding.
__global__ __launch_bounds__(256, 8) void dcn_kernel(
    const float4* __restrict__ img,
    const float* __restrict__ offset,
    const float* __restrict__ mask,
    const float* __restrict__ weight,
    const float* __restrict__ bias,
    float* __restrict__ out) {
    __shared__ float wk[KK];
    __shared__ float red[3][4][64];

    const int t = threadIdx.x;
    if (t < KK) wk[t] = weight[t];
    __syncthreads();

    const int w = t >> 6;
    const int lane = t & 63;
    const int b = blockIdx.y;
    const int pix0 = blockIdx.x * 64;
    const int pix = pix0 + lane;
    const int ho = pix >> 8;
    const int wo = pix & 255;

    // k-range for this wave: [0,21) [21,41) [41,61) [61,81)
    const int kbeg = w * 20 + (w ? 1 : 0);
    const int kend = kbeg + (w ? 20 : 21);
    int ky = kbeg / 9;
    int kx = kbeg - ky * 9;

    const float* op = offset + (size_t)b * 2 * KK * PLANE + (size_t)(2 * kbeg) * PLANE + pix;
    const float* mp = mask + (size_t)b * KK * PLANE + (size_t)kbeg * PLANE + pix;
    const float4* ib = img + (size_t)b * PLANE;

    float ax = 0.f, ay = 0.f, az = 0.f;

#pragma unroll 4
    for (int k = kbeg; k < kend; ++k) {
        float dy = op[0];
        float dx = op[PLANE];
        float m = mp[0] * wk[k];
        op += 2 * PLANE;
        mp += PLANE;

        float py = (float)(ho - 4 + ky) + dy;
        float px = (float)(wo - 4 + kx) + dx;
        float y0f = floorf(py), x0f = floorf(px);
        float wy = py - y0f, wx = px - x0f;
        int y0 = (int)y0f, x0 = (int)x0f;
        int y1 = y0 + 1, x1 = x0 + 1;

        // validity folded into separable bilinear weights (branch-free)
        float a0 = ((unsigned)y0 < (unsigned)HH) ? (1.f - wy) : 0.f;
        float a1 = ((unsigned)y1 < (unsigned)HH) ? wy : 0.f;
        float b0 = ((unsigned)x0 < (unsigned)WW) ? (1.f - wx) : 0.f;
        float b1 = ((unsigned)x1 < (unsigned)WW) ? wx : 0.f;

        int y0c = min(max(y0, 0), HH - 1) * WW;
        int y1c = min(max(y1, 0), HH - 1) * WW;
        int x0c = min(max(x0, 0), WW - 1);
        int x1c = min(max(x1, 0), WW - 1);

        float w00 = a0 * b0 * m;
        float w01 = a0 * b1 * m;
        float w10 = a1 * b0 * m;
        float w11 = a1 * b1 * m;

        float4 v00 = ib[y0c + x0c];
        float4 v01 = ib[y0c + x1c];
        float4 v10 = ib[y1c + x0c];
        float4 v11 = ib[y1c + x1c];
        ax = fmaf(w00, v00.x, ax);
        ay = fmaf(w00, v00.y, ay);
        az = fmaf(w00, v00.z, az);
        ax = fmaf(w01, v01.x, ax);
        ay = fmaf(w01, v01.y, ay);
        az = fmaf(w01, v01.z, az);
        ax = fmaf(w10, v10.x, ax);
        ay = fmaf(w10, v10.y, ay);
        az = fmaf(w10, v10.z, az);
        ax = fmaf(w11, v11.x, ax);
        ay = fmaf(w11, v11.y, ay);
        az = fmaf(w11, v11.z, az);

        if (++kx == 9) {
            kx = 0;
            ++ky;
        }
    }

    red[0][w][lane] = ax;
    red[1][w][lane] = ay;
    red[2][w][lane] = az;
    __syncthreads();

    if (t < 192) {
        const int c = t >> 6;
        const int l = t & 63;
        float s = red[c][0][l] + red[c][1][l] + red[c][2][l] + red[c][3][l] + bias[0];
        out[(size_t)b * 3 * PLANE + (size_t)c * PLANE + pix0 + l] = s;
    }
}

extern "C" void kernel_launch(void* const* d_in, const int* in_sizes, int n_in,
                              void* d_out, int out_size, void* d_ws, size_t ws_size,
                              hipStream_t stream) {
    const float* input = (const float*)d_in[0];
    const float* offset = (const float*)d_in[1];
    const float* mask = (const float*)d_in[2];
    const float* weight = (const float*)d_in[3];
    const float* bias = (const float*)d_in[4];
    float* out = (float*)d_out;

    const int B = in_sizes[0] / (3 * PLANE);  // 2
    float4* img = (float4*)d_ws;

    pack_kernel<<<B * PLANE / 256, 256, 0, stream>>>(input, img);
    dim3 grid(PLANE / 64, B);
    dcn_kernel<<<grid, 256, 0, stream>>>(img, offset, mask, weight, bias, out);
}

// Round 3
// 178.433 us; speedup vs baseline: 1.2106x; 1.2106x over previous
//
#include <hip/hip_runtime.h>
#include <hip/hip_fp16.h>

#define HH 256
#define WW 256
#define KK 81
#define PLANE (HH * WW)
#define SLACK 10          // tile halo: rows [ho-10, ho+10], cols [xb, xb+83]
#define TR 21             // tile rows
#define TC 84             // tile cols (64-px strip + 4+SLACK halo each side)

// Pack [B,3,H,W] fp32 -> [B,H,W] ushort4 of fp16 (c0,c1,c2,0): one 8 B cell
// carries all 3 color groups for a pixel.
__global__ __launch_bounds__(256) void pack_kernel(const float* __restrict__ in,
                                                   ushort4* __restrict__ img) {
    int idx = blockIdx.x * 256 + threadIdx.x;  // b*PLANE + pix
    int b = idx >> 16;
    int pix = idx & 0xFFFF;
    const float* base = in + (size_t)b * 3 * PLANE + pix;
    _Float16 h0 = (_Float16)base[0];
    _Float16 h1 = (_Float16)base[PLANE];
    _Float16 h2 = (_Float16)base[2 * PLANE];
    ushort4 u;
    u.x = __builtin_bit_cast(unsigned short, h0);
    u.y = __builtin_bit_cast(unsigned short, h1);
    u.z = __builtin_bit_cast(unsigned short, h2);
    u.w = 0;
    img[idx] = u;
}

__device__ __forceinline__ float h2f(unsigned short u) {
    _Float16 h = __builtin_bit_cast(_Float16, u);
    return (float)h;
}

// Block = 64-pixel strip of one output row. 4 waves split the 81 taps
// (21/20/20/20). All bilinear gathers hit a shared LDS tile of the input
// (fp16x4, 14 KB); out-of-tile lanes (|offset|>~6, ~never) fall back to a
// global gather. 8 blocks/CU -> 32 waves/CU.
__global__ __launch_bounds__(256, 8) void dcn_kernel(
    const ushort4* __restrict__ img,
    const float* __restrict__ offset,
    const float* __restrict__ mask,
    const float* __restrict__ weight,
    const float* __restrict__ bias,
    float* __restrict__ out) {
    __shared__ ushort4 tile[TR * TC];
    __shared__ float red[3][4][64];
    __shared__ float wk[KK];

    const int t = threadIdx.x;
    if (t < KK) wk[t] = weight[t];

    const int b = blockIdx.y;
    const int pix0 = blockIdx.x * 64;
    const int ho = pix0 >> 8;                 // uniform: strip stays in one row
    const int xb = (pix0 & 255) - SLACK;      // tile col 0 = image col xb
    const int yb = ho - SLACK;                // tile row 0 = image row yb
    const ushort4* ib = img + (size_t)b * PLANE;

    // stage the tile: 1764 cells, coalesced 8 B loads
    for (int i = 0; i < 7; ++i) {
        int cid = t + i * 256;
        if (cid < TR * TC) {
            int r = cid / TC;
            int c = cid - r * TC;
            int iy = min(max(yb + r, 0), HH - 1);
            int ix = min(max(xb + c, 0), WW - 1);
            tile[cid] = ib[iy * WW + ix];
        }
    }
    __syncthreads();

    const int w = t >> 6;
    const int lane = t & 63;
    const int wo = (pix0 & 255) + lane;
    const int pix = pix0 + lane;

    // k-range per wave: [0,21) [21,41) [41,61) [61,81)
    const int kbeg = w * 20 + (w ? 1 : 0);
    const int kend = kbeg + (w ? 20 : 21);
    int ky = kbeg / 9;
    int kx = kbeg - ky * 9;

    const float* op = offset + (size_t)b * 2 * KK * PLANE + (size_t)(2 * kbeg) * PLANE + pix;
    const float* mp = mask + (size_t)b * KK * PLANE + (size_t)kbeg * PLANE + pix;

    float ax = 0.f, ay = 0.f, az = 0.f;

#pragma unroll 4
    for (int k = kbeg; k < kend; ++k) {
        float dy = op[0];
        float dx = op[PLANE];
        float m = mp[0] * wk[k];
        op += 2 * PLANE;
        mp += PLANE;

        float py = (float)(ho - 4 + ky) + dy;
        float px = (float)(wo - 4 + kx) + dx;
        float y0f = floorf(py), x0f = floorf(px);
        float wy = py - y0f, wx = px - x0f;
        int y0 = (int)y0f, x0 = (int)x0f;
        int y1 = y0 + 1, x1 = x0 + 1;

        // validity folded into separable bilinear weights (branch-free)
        float a0 = ((unsigned)y0 < (unsigned)HH) ? (1.f - wy) : 0.f;
        float a1 = ((unsigned)y1 < (unsigned)HH) ? wy : 0.f;
        float b0 = ((unsigned)x0 < (unsigned)WW) ? (1.f - wx) : 0.f;
        float b1 = ((unsigned)x1 < (unsigned)WW) ? wx : 0.f;

        int y0c = min(max(y0, 0), HH - 1);
        int y1c = min(max(y1, 0), HH - 1);
        int x0c = min(max(x0, 0), WW - 1);
        int x1c = min(max(x1, 0), WW - 1);

        int r0 = y0c - yb, r1 = y1c - yb;
        int c0 = x0c - xb, c1 = x1c - xb;
        bool ok = ((unsigned)r0 < TR) & ((unsigned)r1 < TR) &
                  ((unsigned)c0 < TC) & ((unsigned)c1 < TC);

        ushort4 v00, v01, v10, v11;
        if (__builtin_expect(__all(ok), 1)) {
            v00 = tile[r0 * TC + c0];
            v01 = tile[r0 * TC + c1];
            v10 = tile[r1 * TC + c0];
            v11 = tile[r1 * TC + c1];
        } else {
            if (ok) {
                v00 = tile[r0 * TC + c0];
                v01 = tile[r0 * TC + c1];
                v10 = tile[r1 * TC + c0];
                v11 = tile[r1 * TC + c1];
            } else {
                v00 = ib[y0c * WW + x0c];
                v01 = ib[y0c * WW + x1c];
                v10 = ib[y1c * WW + x0c];
                v11 = ib[y1c * WW + x1c];
            }
        }

        float w00 = a0 * b0 * m;
        float w01 = a0 * b1 * m;
        float w10 = a1 * b0 * m;
        float w11 = a1 * b1 * m;

        ax = fmaf(w00, h2f(v00.x), ax);
        ay = fmaf(w00, h2f(v00.y), ay);
        az = fmaf(w00, h2f(v00.z), az);
        ax = fmaf(w01, h2f(v01.x), ax);
        ay = fmaf(w01, h2f(v01.y), ay);
        az = fmaf(w01, h2f(v01.z), az);
        ax = fmaf(w10, h2f(v10.x), ax);
        ay = fmaf(w10, h2f(v10.y), ay);
        az = fmaf(w10, h2f(v10.z), az);
        ax = fmaf(w11, h2f(v11.x), ax);
        ay = fmaf(w11, h2f(v11.y), ay);
        az = fmaf(w11, h2f(v11.z), az);

        if (++kx == 9) {
            kx = 0;
            ++ky;
        }
    }

    red[0][w][lane] = ax;
    red[1][w][lane] = ay;
    red[2][w][lane] = az;
    __syncthreads();

    if (t < 192) {
        const int c = t >> 6;
        const int l = t & 63;
        float s = red[c][0][l] + red[c][1][l] + red[c][2][l] + red[c][3][l] + bias[0];
        out[(size_t)b * 3 * PLANE + (size_t)c * PLANE + pix0 + l] = s;
    }
}

extern "C" void kernel_launch(void* const* d_in, const int* in_sizes, int n_in,
                              void* d_out, int out_size, void* d_ws, size_t ws_size,
                              hipStream_t stream) {
    const float* input = (const float*)d_in[0];
    const float* offset = (const float*)d_in[1];
    const float* mask = (const float*)d_in[2];
    const float* weight = (const float*)d_in[3];
    const float* bias = (const float*)d_in[4];
    float* out = (float*)d_out;

    const int B = in_sizes[0] / (3 * PLANE);  // 2
    ushort4* img = (ushort4*)d_ws;            // 1 MB packed fp16 image

    pack_kernel<<<B * PLANE / 256, 256, 0, stream>>>(input, img);
    dim3 grid(PLANE / 64, B);
    dcn_kernel<<<grid, 256, 0, stream>>>(img, offset, mask, weight, bias, out);
}

// Round 5
// 173.064 us; speedup vs baseline: 1.2481x; 1.0310x over previous
//
#include <hip/hip_runtime.h>
#include <hip/hip_fp16.h>

#define HH 256
#define WW 256
#define KK 81
#define PLANE (HH * WW)
#define SLACK 10          // tile halo: rows [ho-10, ho+10], cols [xb, xb+83]
#define TR 21             // tile rows
#define TC 84             // tile cols (64-px strip + 4+SLACK halo each side)
#define TAB (TR * TC)     // 1764 cells per plane

// Pack [B,3,H,W] fp32 -> [B,H,W] ushort4 of fp16 (c0,c1,c2,0): one 8 B cell
// carries all 3 color groups for a pixel.
__global__ __launch_bounds__(256) void pack_kernel(const float* __restrict__ in,
                                                   ushort4* __restrict__ img) {
    int idx = blockIdx.x * 256 + threadIdx.x;  // b*PLANE + pix
    int b = idx >> 16;
    int pix = idx & 0xFFFF;
    const float* base = in + (size_t)b * 3 * PLANE + pix;
    _Float16 h0 = (_Float16)base[0];
    _Float16 h1 = (_Float16)base[PLANE];
    _Float16 h2 = (_Float16)base[2 * PLANE];
    ushort4 u;
    u.x = __builtin_bit_cast(unsigned short, h0);
    u.y = __builtin_bit_cast(unsigned short, h1);
    u.z = __builtin_bit_cast(unsigned short, h2);
    u.w = 0;
    img[idx] = u;
}

__device__ __forceinline__ void acc3(float w, unsigned int pa, unsigned int pb,
                                     float& ax, float& ay, float& az) {
    __half2 ha = __builtin_bit_cast(__half2, pa);
    __half2 hb = __builtin_bit_cast(__half2, pb);
    ax = fmaf(w, __low2float(ha), ax);   // v_fma_mix_f32 (lo)
    ay = fmaf(w, __high2float(ha), ay);  // v_fma_mix_f32 (hi)
    az = fmaf(w, __low2float(hb), az);
}

// Block = 64-pixel strip of one output row. 4 waves split the 81 taps
// (21/20/20/20) and LDS-reduce. Input tile staged ZERO-PADDED in LDS as two
// 4 B planes (fp16x2 c0c1, fp16 c2): tile row r == image row yb+r exactly
// (zeros outside the image), so unclamped index math is correct and
// out-of-image corners contribute 0 through the data (DCNv2 semantics).
__global__ __launch_bounds__(256, 8) void dcn_kernel(
    const ushort4* __restrict__ img,
    const float* __restrict__ offset,
    const float* __restrict__ mask,
    const float* __restrict__ weight,
    const float* __restrict__ bias,
    float* __restrict__ out) {
    __shared__ unsigned int tile2[2 * TAB + 96];  // [0,TAB): c0c1  [TAB,2TAB): c2
    __shared__ float red[3][4][64];
    __shared__ float wk[KK];

    const int t = threadIdx.x;
    if (t < KK) wk[t] = weight[t];

    const int b = blockIdx.y;
    const int pix0 = blockIdx.x * 64;
    const int ho = pix0 >> 8;                 // strip stays in one output row
    const int xb = (pix0 & 255) - SLACK;
    const int yb = ho - SLACK;
    const ushort4* ib = img + (size_t)b * PLANE;

    // stage tile: 1764 cells, zero outside the image
    for (int i = 0; i < 7; ++i) {
        int cid = t + i * 256;
        if (cid < TAB) {
            int r = cid / TC;
            int c = cid - r * TC;
            int iy = yb + r;
            int ix = xb + c;
            unsigned int pa = 0, pb = 0;
            if (((unsigned)iy < (unsigned)HH) & ((unsigned)ix < (unsigned)WW)) {
                ushort4 u = ib[iy * WW + ix];
                pa = (unsigned int)u.x | ((unsigned int)u.y << 16);
                pb = (unsigned int)u.z;
            }
            tile2[cid] = pa;
            tile2[cid + TAB] = pb;
        }
    }
    __syncthreads();

    const int w = t >> 6;
    const int lane = t & 63;
    const int wo = (pix0 & 255) + lane;
    const int pix = pix0 + lane;

    // k-range per wave: [0,21) [21,41) [41,61) [61,81)
    const int kbeg = w * 20 + (w ? 1 : 0);
    const int kend = kbeg + (w ? 20 : 21);
    int ky = kbeg / 9;
    int kx = kbeg - ky * 9;

    const float* op = offset + (size_t)b * 2 * KK * PLANE + (size_t)(2 * kbeg) * PLANE + pix;
    const float* mp = mask + (size_t)b * KK * PLANE + (size_t)kbeg * PLANE + pix;

    const float wof = (float)wo;
    float ax = 0.f, ay = 0.f, az = 0.f;

#pragma unroll 4
    for (int k = kbeg; k < kend; ++k) {
        float dy = op[0];
        float dx = op[PLANE];
        float m = mp[0] * wk[k];
        op += 2 * PLANE;
        mp += PLANE;

        float py = (float)(ho - 4 + ky) + dy;
        float px = wof + ((float)(kx - 4) + dx);
        float y0f = floorf(py), x0f = floorf(px);
        float wy = py - y0f, wx = px - x0f;
        int y0 = (int)y0f, x0 = (int)x0f;

        // unclamped tile coords: tile row r == image row yb+r (zero-padded)
        int r0 = y0 - yb;
        int c0 = x0 - xb;
        bool ok = ((unsigned)r0 < (TR - 1)) & ((unsigned)c0 < (TC - 1));

        float w1y = wy * m, w0y = m - w1y;      // a0*m, a1*m (validity via data)
        float w00 = w0y * (1.f - wx), w01 = w0y * wx;
        float w10 = w1y * (1.f - wx), w11 = w1y * wx;

        unsigned int pa00, pa01, pa10, pa11, pb00, pb01, pb10, pb11;
        if (__builtin_expect(__all(ok), 1)) {
            int i00 = r0 * TC + c0;
            pa00 = tile2[i00];
            pa01 = tile2[i00 + 1];
            pa10 = tile2[i00 + TC];
            pa11 = tile2[i00 + TC + 1];
            pb00 = tile2[i00 + TAB];
            pb01 = tile2[i00 + TAB + 1];
            pb10 = tile2[i00 + TAB + TC];
            pb11 = tile2[i00 + TAB + TC + 1];
        } else {
            if (ok) {
                int i00 = r0 * TC + c0;
                pa00 = tile2[i00];
                pa01 = tile2[i00 + 1];
                pa10 = tile2[i00 + TC];
                pa11 = tile2[i00 + TC + 1];
                pb00 = tile2[i00 + TAB];
                pb01 = tile2[i00 + TAB + 1];
                pb10 = tile2[i00 + TAB + TC];
                pb11 = tile2[i00 + TAB + TC + 1];
            } else {
                // fully clamped + validity-masked global fallback
                int y1 = y0 + 1, x1 = x0 + 1;
                float va0 = ((unsigned)y0 < (unsigned)HH) ? 1.f : 0.f;
                float va1 = ((unsigned)y1 < (unsigned)HH) ? 1.f : 0.f;
                float vb0 = ((unsigned)x0 < (unsigned)WW) ? 1.f : 0.f;
                float vb1 = ((unsigned)x1 < (unsigned)WW) ? 1.f : 0.f;
                w00 *= va0 * vb0;
                w01 *= va0 * vb1;
                w10 *= va1 * vb0;
                w11 *= va1 * vb1;
                int y0c = min(max(y0, 0), HH - 1);
                int y1c = min(max(y1, 0), HH - 1);
                int x0c = min(max(x0, 0), WW - 1);
                int x1c = min(max(x1, 0), WW - 1);
                ushort4 g00 = ib[y0c * WW + x0c];
                ushort4 g01 = ib[y0c * WW + x1c];
                ushort4 g10 = ib[y1c * WW + x0c];
                ushort4 g11 = ib[y1c * WW + x1c];
                pa00 = (unsigned int)g00.x | ((unsigned int)g00.y << 16); pb00 = g00.z;
                pa01 = (unsigned int)g01.x | ((unsigned int)g01.y << 16); pb01 = g01.z;
                pa10 = (unsigned int)g10.x | ((unsigned int)g10.y << 16); pb10 = g10.z;
                pa11 = (unsigned int)g11.x | ((unsigned int)g11.y << 16); pb11 = g11.z;
            }
        }

        acc3(w00, pa00, pb00, ax, ay, az);
        acc3(w01, pa01, pb01, ax, ay, az);
        acc3(w10, pa10, pb10, ax, ay, az);
        acc3(w11, pa11, pb11, ax, ay, az);

        if (++kx == 9) {
            kx = 0;
            ++ky;
        }
    }

    red[0][w][lane] = ax;
    red[1][w][lane] = ay;
    red[2][w][lane] = az;
    __syncthreads();

    if (t < 192) {
        const int c = t >> 6;
        const int l = t & 63;
        float s = red[c][0][l] + red[c][1][l] + red[c][2][l] + red[c][3][l] + bias[0];
        out[(size_t)b * 3 * PLANE + (size_t)c * PLANE + pix0 + l] = s;
    }
}

extern "C" void kernel_launch(void* const* d_in, const int* in_sizes, int n_in,
                              void* d_out, int out_size, void* d_ws, size_t ws_size,
                              hipStream_t stream) {
    const float* input = (const float*)d_in[0];
    const float* offset = (const float*)d_in[1];
    const float* mask = (const float*)d_in[2];
    const float* weight = (const float*)d_in[3];
    const float* bias = (const float*)d_in[4];
    float* out = (float*)d_out;

    const int B = in_sizes[0] / (3 * PLANE);  // 2
    ushort4* img = (ushort4*)d_ws;            // 1 MB packed fp16 image

    pack_kernel<<<B * PLANE / 256, 256, 0, stream>>>(input, img);
    dim3 grid(PLANE / 64, B);
    dcn_kernel<<<grid, 256, 0, stream>>>(img, offset, mask, weight, bias, out);
}